// Round 16
// baseline (79.257 us; speedup 1.0000x reference)
//
#include <hip/hip_runtime.h>
#include <hip/hip_bf16.h>

#define GD     50          // grid cells per dim
#define NC     (GD*GD*GD)  // 125000
#define CHUNK  250         // cells per offsets block; 250%50==0 keeps x-rows intact
#define CAPK   256         // in-radius candidate capacity per centroid
#define RADIUS_F 0.2f
#define R2SAFE 0.0401f

typedef unsigned long long ull;
typedef __attribute__((ext_vector_type(4))) _Float16 f16x4;
typedef __attribute__((ext_vector_type(8))) _Float16 f16x8;
typedef __attribute__((ext_vector_type(4))) float    f32x4;

__device__ __forceinline__ int cellcoord(float v) {
    int c = (int)floorf((v + 5.0f) * 5.0f);
    return min(max(c, 0), GD - 1);
}

// Fragment-order weight layout in wf16 (13312 f16):
//   [0,1024)      F1 [nn=4][lane=64][4]
//   [1024,3072)   FA2[nn=4][lane=64][8]
//   [3072,5120)   FB2[nn=4][lane=64][8]
//   [5120,9216)   FA3[nn=8][lane=64][8]
//   [9216,13312)  FB3[nn=8][lane=64][8]

// -------- K0: zero cellCnt + cursor ---------------------------------------
__global__ void sa_zero_kernel(int4* __restrict__ dst, int n4) {
    int i = blockIdx.x * blockDim.x + threadIdx.x;
    int stride = gridDim.x * blockDim.x;
    for (; i < n4; i += stride) dst[i] = make_int4(0, 0, 0, 0);
}

// -------- K1: pack pt4, cell ids, cell counts, frag-order f16 weights -----
__global__ void sa_prep_kernel(const float* __restrict__ vtx,
                               float4* __restrict__ pt4,
                               int* __restrict__ cid,
                               int* __restrict__ cellCnt,
                               int N,
                               const float* __restrict__ W1,
                               const float* __restrict__ W2,
                               const float* __restrict__ W3,
                               _Float16* __restrict__ wf16) {
    int i = blockIdx.x * blockDim.x + threadIdx.x;
    int stride = gridDim.x * blockDim.x;
    for (int p = i; p < N; p += stride) {
        float x = vtx[3 * p], y = vtx[3 * p + 1], z = vtx[3 * p + 2];
        float sn = fmaf(z, z, fmaf(y, y, x * x));
        pt4[p] = make_float4(x, y, z, sn);
        int cc = (cellcoord(z) * GD + cellcoord(y)) * GD + cellcoord(x);
        cid[p] = cc;
        atomicAdd(&cellCnt[cc], 1);
    }
    for (int e = i; e < 1024; e += stride) {
        int nn = e >> 8, lane = (e >> 2) & 63, j = e & 3;
        int col = nn * 16 + (lane & 15), k = (lane >> 4) * 4 + j;
        wf16[e] = (k < 6) ? (_Float16)W1[k * 64 + col] : (_Float16)0.f;
    }
    for (int e = i; e < 2048; e += stride) {
        int nn = e >> 9, lane = (e >> 3) & 63, j = e & 7;
        int col = nn * 16 + (lane & 15), k = (lane >> 4) * 8 + j;
        wf16[1024 + e] = (_Float16)W2[k * 64 + col];
        wf16[3072 + e] = (_Float16)W2[(k + 32) * 64 + col];
    }
    for (int e = i; e < 4096; e += stride) {
        int nn = e >> 9, lane = (e >> 3) & 63, j = e & 7;
        int col = nn * 16 + (lane & 15), k = (lane >> 4) * 8 + j;
        wf16[5120 + e] = (_Float16)W3[k * 128 + col];
        wf16[9216 + e] = (_Float16)W3[(k + 32) * 128 + col];
    }
}

// -------- K2: CSR offsets, 250-cell x-row-aligned chunks; also cellEnd ----
__global__ __launch_bounds__(256) void sa_offsets_kernel(
    const int* __restrict__ cellCnt, int* __restrict__ cellStart,
    int* __restrict__ cellEnd, int* __restrict__ cellCur,
    int* __restrict__ cursor) {
    __shared__ int sc[256];
    __shared__ int base_s;
    int t = threadIdx.x;
    int i = blockIdx.x * CHUNK + t;
    int c = (t < CHUNK) ? cellCnt[i] : 0;
    sc[t] = c;
    __syncthreads();
    for (int d = 1; d < 256; d <<= 1) {
        int o = (t >= d) ? sc[t - d] : 0;
        __syncthreads();
        sc[t] += o;
        __syncthreads();
    }
    if (t == 255) base_s = atomicAdd(cursor, sc[255]);
    __syncthreads();
    int start = base_s + sc[t] - c;
    if (t < CHUNK) {
        cellStart[i] = start;
        cellEnd[i] = start + c;
        cellCur[i] = start;
    }
}

// -------- K3: scatter points; also materialize centroid positions ---------
__global__ void sa_scatter_kernel(const float4* __restrict__ pt4,
                                  const int* __restrict__ cid,
                                  int* __restrict__ cellCur,
                                  float4* __restrict__ sorted4,
                                  int* __restrict__ sidx,
                                  const int* __restrict__ cidx,
                                  float4* __restrict__ cpos4,
                                  int N, int M) {
    int p = blockIdx.x * blockDim.x + threadIdx.x;
    if (p < N) {
        int pos = atomicAdd(&cellCur[cid[p]], 1);
        sorted4[pos] = pt4[p];
        sidx[pos] = p;
    }
    if (p < M) cpos4[p] = pt4[cidx[p]];
}

// -------- K4: fused collect + top-64 + MLP, weights LDS-staged ------------
// 4 centroids/block (1 per wave), 256 threads. LDS ~62.5KB -> 2 blocks/CU.
// Per-wave 8KB smem region phase-aliased: keys[0,2560) -> featb[4096,6144)
// -> h[0,8192). Weights staged once per block, barrier BEFORE collect.
__global__ __launch_bounds__(256) void sa_fused3_kernel(
    const float4* __restrict__ pt4, const float4* __restrict__ cpos4,
    const float4* __restrict__ sorted4, const int* __restrict__ sidx,
    const int* __restrict__ cellStart, const int* __restrict__ cellEnd,
    const _Float16* __restrict__ wf16,
    const float* __restrict__ b1, const float* __restrict__ b2,
    const float* __restrict__ b3, float* __restrict__ out) {

    __shared__ __align__(16) _Float16 Wf[13312];     // frag-order weights
    __shared__ __align__(16) float    Wb[256];       // b1|b2|b3
    __shared__ __align__(16) char smem[4][8192];
    __shared__ int selb[4][64];
    __shared__ int chdesc[4][64];
    __shared__ int scnt_s[4];

    int t = threadIdx.x, w = t >> 6, lane = t & 63;
    int r16 = lane & 15, g = lane >> 4;
    int c = blockIdx.x * 4 + w;

    // ---- stage weights + biases (uniform work), one cheap barrier ----
    {
        const uint4* src = (const uint4*)wf16;
        uint4* dst = (uint4*)Wf;
        for (int i = t; i < 13312 / 8; i += 256) dst[i] = src[i];
        if (t < 64) Wb[t] = b1[t];
        else if (t < 128) Wb[t] = b2[t - 64];
        else Wb[t] = b3[t - 128];
        if (t < 4) scnt_s[t] = 0;
    }
    __syncthreads();

    float4 cc = cpos4[c];
    ull* key = (ull*)smem[w];
    _Float16* featb = (_Float16*)(smem[w] + 4096);
    _Float16* h = (_Float16*)smem[w];

    // ---- row bounds (<=9 contiguous x-runs), AABB-pruned ----
    int cx = cellcoord(cc.x), cy = cellcoord(cc.y), cz = cellcoord(cc.z);
    int x0 = max(cx - 1, 0), x1 = min(cx + 1, GD - 1), lx = x1 - x0 + 1;
    int y0 = max(cy - 1, 0), y1 = min(cy + 1, GD - 1), ly = y1 - y0 + 1;
    int z0 = max(cz - 1, 0), z1 = min(cz + 1, GD - 1), lz = z1 - z0 + 1;
    int nrow = ly * lz;

    int rstart = 0, rlen = 0;
    if (lane < nrow) {
        int iy = lane % ly, iz = lane / ly;
        int gy = y0 + iy, gz = z0 + iz;
        float ylo = (gy == 0) ? -1e30f : gy * 0.2f - 5.0f;
        float yhi = (gy == GD - 1) ? 1e30f : (gy + 1) * 0.2f - 5.0f;
        float zlo = (gz == 0) ? -1e30f : gz * 0.2f - 5.0f;
        float zhi = (gz == GD - 1) ? 1e30f : (gz + 1) * 0.2f - 5.0f;
        float dy = fmaxf(0.f, fmaxf(ylo - cc.y, cc.y - yhi));
        float dz = fmaxf(0.f, fmaxf(zlo - cc.z, cc.z - zhi));
        if (fmaf(dz, dz, dy * dy) <= R2SAFE) {
            int cell0 = (gz * GD + gy) * GD + x0;
            int cellL = cell0 + (lx - 1);
            rstart = cellStart[cell0];
            rlen = cellEnd[cellL] - rstart;
        }
    }

    // ---- chunk-descriptor table (start | len<<20), 64-wide chunks ----
    int nch = (rlen + 63) >> 6;
    int ip = nch;
#pragma unroll
    for (int d = 1; d < 16; d <<= 1) {
        int o = __shfl_up(ip, d);
        if (lane >= d) ip += o;
    }
    int C = __shfl(ip, nrow - 1);
    int ebase = ip - nch;
    if (lane < nrow) {
        for (int k = 0; k < nch; ++k) {
            int st = rstart + (k << 6);
            int ln = min(64, rlen - (k << 6));
            chdesc[w][ebase + k] = st | (ln << 20);
        }
    }

    // ---- stream chunks ----
#pragma unroll 2
    for (int ch = 0; ch < C; ++ch) {
        int d0 = chdesc[w][ch];
        int st = d0 & 0xFFFFF, ln = d0 >> 20;
        if (lane < ln) {
            int sp = st + lane;
            float4 p = sorted4[sp];
            int pid = sidx[sp];
            float dot = fmaf(p.z, cc.z, fmaf(p.y, cc.y, p.x * cc.x));
            float tt = fmaf(-2.f, dot, cc.w) + p.w;
            if (tt <= R2SAFE) {
                float dd = sqrtf(fabsf(tt));
                if (dd <= RADIUS_F) {
                    int slot = atomicAdd(&scnt_s[w], 1);
                    if (slot < CAPK)
                        key[slot] = (((ull)__float_as_uint(dd)) << 32) | (unsigned)pid;
                }
            }
        }
    }

    // ---- top-64: padded, unroll-8 rank count ----
    int n = min(scnt_s[w], CAPK);
    int nsel = min(n, 64);
    int n64 = (n + 63) & ~63;
    if (lane < n64 - n) key[n + lane] = ~0ull;   // sentinels rank last
    if (n > 64) {
        for (int i = lane; i < n; i += 64) {
            ull ki = key[i];
            int r = 0;
            for (int j = 0; j < n64; j += 8) {
#pragma unroll
                for (int jj = 0; jj < 8; ++jj)
                    r += (key[j + jj] < ki) ? 1 : 0;
            }
            if (r < 64) selb[w][r] = (int)(unsigned)(ki & 0xffffffffu);
        }
    } else {
        for (int i = lane; i < n; i += 64)
            selb[w][i] = (int)(unsigned)(key[i] & 0xffffffffu);
    }

    // ---- gather features -> featb [64][16] f16, zero-padded ----
    {
        _Float16 z = (_Float16)0.f;
        f16x8 lo8 = {z, z, z, z, z, z, z, z};
        if (lane < nsel) {
            float4 p = pt4[selb[w][lane]];
            lo8[0] = (_Float16)p.x; lo8[1] = (_Float16)p.y; lo8[2] = (_Float16)p.z;
            lo8[3] = (_Float16)(p.x - cc.x);
            lo8[4] = (_Float16)(p.y - cc.y);
            lo8[5] = (_Float16)(p.z - cc.z);
        }
        f16x8 hi8 = {z, z, z, z, z, z, z, z};
        *(f16x8*)&featb[lane * 16 + 0] = lo8;
        *(f16x8*)&featb[lane * 16 + 8] = hi8;
    }

    // ---- L1: feat @ W1 -> relu -> h swizzled ----
    {
        f16x4 a1[4];
#pragma unroll
        for (int m = 0; m < 4; ++m)
            a1[m] = *(const f16x4*)&featb[(m * 16 + r16) * 16 + g * 4];
#pragma unroll
        for (int nn = 0; nn < 4; ++nn) {
            int col = nn * 16 + r16;
            f16x4 b = *(const f16x4*)&Wf[(nn * 64 + lane) * 4];
            float bb = Wb[col];
#pragma unroll
            for (int m = 0; m < 4; ++m) {
                f32x4 acc = {bb, bb, bb, bb};
                acc = __builtin_amdgcn_mfma_f32_16x16x16f16(a1[m], b, acc, 0, 0, 0);
#pragma unroll
                for (int reg = 0; reg < 4; ++reg) {
                    int row = m * 16 + g * 4 + reg;
                    h[row * 64 + (col ^ ((row & 7) << 3))] =
                        (_Float16)fmaxf(acc[reg], 0.f);
                }
            }
        }
    }

    // ---- L2: h @ W2 -> relu -> h ----
    {
        f16x8 a2[4][2];
#pragma unroll
        for (int m = 0; m < 4; ++m)
#pragma unroll
            for (int kt = 0; kt < 2; ++kt) {
                int row = m * 16 + r16;
                int k0 = kt * 32 + g * 8;
                a2[m][kt] = *(const f16x8*)&h[row * 64 + (k0 ^ ((row & 7) << 3))];
            }
#pragma unroll
        for (int nn = 0; nn < 4; ++nn) {
            int col = nn * 16 + r16;
            f16x8 bA = *(const f16x8*)&Wf[1024 + (nn * 64 + lane) * 8];
            f16x8 bB = *(const f16x8*)&Wf[3072 + (nn * 64 + lane) * 8];
            float bb = Wb[64 + col];
#pragma unroll
            for (int m = 0; m < 4; ++m) {
                f32x4 acc = {bb, bb, bb, bb};
                acc = __builtin_amdgcn_mfma_f32_16x16x32_f16(a2[m][0], bA, acc, 0, 0, 0);
                acc = __builtin_amdgcn_mfma_f32_16x16x32_f16(a2[m][1], bB, acc, 0, 0, 0);
#pragma unroll
                for (int reg = 0; reg < 4; ++reg) {
                    int row = m * 16 + g * 4 + reg;
                    h[row * 64 + (col ^ ((row & 7) << 3))] =
                        (_Float16)fmaxf(acc[reg], 0.f);
                }
            }
        }
    }

    // ---- L3: h @ W3 + mask + max over rows ----
    {
        f16x8 a3[4][2];
#pragma unroll
        for (int m = 0; m < 4; ++m)
#pragma unroll
            for (int kt = 0; kt < 2; ++kt) {
                int row = m * 16 + r16;
                int k0 = kt * 32 + g * 8;
                a3[m][kt] = *(const f16x8*)&h[row * 64 + (k0 ^ ((row & 7) << 3))];
            }
        float ninf = __int_as_float(0xff800000);
#pragma unroll
        for (int nn = 0; nn < 8; ++nn) {
            int col = nn * 16 + r16;
            f16x8 bA = *(const f16x8*)&Wf[5120 + (nn * 64 + lane) * 8];
            f16x8 bB = *(const f16x8*)&Wf[9216 + (nn * 64 + lane) * 8];
            float bb = Wb[128 + col];
            float vm = ninf;
#pragma unroll
            for (int m = 0; m < 4; ++m) {
                f32x4 acc = {bb, bb, bb, bb};
                acc = __builtin_amdgcn_mfma_f32_16x16x32_f16(a3[m][0], bA, acc, 0, 0, 0);
                acc = __builtin_amdgcn_mfma_f32_16x16x32_f16(a3[m][1], bB, acc, 0, 0, 0);
#pragma unroll
                for (int reg = 0; reg < 4; ++reg) {
                    int row = m * 16 + g * 4 + reg;
                    if (row < nsel) vm = fmaxf(vm, acc[reg]);
                }
            }
            vm = fmaxf(vm, __shfl_xor(vm, 16));
            vm = fmaxf(vm, __shfl_xor(vm, 32));
            if (lane < 16) out[(size_t)c * 128 + nn * 16 + lane] = vm;
        }
    }
}

extern "C" void kernel_launch(void* const* d_in, const int* in_sizes, int n_in,
                              void* d_out, int out_size, void* d_ws, size_t ws_size,
                              hipStream_t stream) {
    const float* vtx = (const float*)d_in[0];
    const int* cidx  = (const int*)d_in[1];
    const float* W1  = (const float*)d_in[2];
    const float* b1  = (const float*)d_in[3];
    const float* W2  = (const float*)d_in[4];
    const float* b2  = (const float*)d_in[5];
    const float* W3  = (const float*)d_in[6];
    const float* b3  = (const float*)d_in[7];
    float* out = (float*)d_out;

    int N = in_sizes[0] / 3;   // 65536
    int M = in_sizes[1];       // 4096

    char* ws = (char*)d_ws;
    size_t off = 0;
    float4* pt4     = (float4*)(ws + off); off += (size_t)N * 16;
    float4* sorted4 = (float4*)(ws + off); off += (size_t)N * 16;
    float4* cpos4   = (float4*)(ws + off); off += (size_t)M * 16;
    int* sidx       = (int*)(ws + off);    off += (size_t)N * 4;
    int* cid        = (int*)(ws + off);    off += (size_t)N * 4;
    int* cellCnt    = (int*)(ws + off);    off += (size_t)NC * 4;
    int* cursor     = (int*)(ws + off);    off += 16;
    int* cellStart  = (int*)(ws + off);    off += (size_t)NC * 4;
    int* cellEnd    = (int*)(ws + off);    off += (size_t)NC * 4;
    int* cellCur    = (int*)(ws + off);    off += (size_t)NC * 4;
    _Float16* wf16  = (_Float16*)(ws + off);

    sa_zero_kernel<<<256, 256, 0, stream>>>((int4*)cellCnt, (NC * 4 + 16) / 16);
    sa_prep_kernel<<<512, 256, 0, stream>>>(vtx, pt4, cid, cellCnt, N,
                                            W1, W2, W3, wf16);
    sa_offsets_kernel<<<NC / CHUNK, 256, 0, stream>>>(cellCnt, cellStart,
                                                      cellEnd, cellCur, cursor);
    sa_scatter_kernel<<<(N + 255) / 256, 256, 0, stream>>>(pt4, cid, cellCur,
                                                           sorted4, sidx,
                                                           cidx, cpos4, N, M);
    sa_fused3_kernel<<<M / 4, 256, 0, stream>>>(pt4, cpos4, sorted4, sidx,
                                                cellStart, cellEnd, wf16,
                                                b1, b2, b3, out);
}

// Round 17
// 68.422 us; speedup vs baseline: 1.1584x; 1.1584x over previous
//
#include <hip/hip_runtime.h>
#include <hip/hip_bf16.h>

#define GD     50          // grid cells per dim
#define NC     (GD*GD*GD)  // 125000
#define CHUNK  250         // cells per offsets block; 250%50==0 keeps x-rows intact
#define CAPK   256         // in-radius candidate capacity per centroid
#define RADIUS_F 0.2f
#define R2SAFE 0.0401f

typedef unsigned long long ull;
typedef __attribute__((ext_vector_type(4))) _Float16 f16x4;
typedef __attribute__((ext_vector_type(8))) _Float16 f16x8;
typedef __attribute__((ext_vector_type(4))) float    f32x4;

__device__ __forceinline__ int cellcoord(float v) {
    int c = (int)floorf((v + 5.0f) * 5.0f);
    return min(max(c, 0), GD - 1);
}

// Fragment-order weight layout in wf16 (13312 f16):
//   [0,1024)      F1 [nn=4][lane=64][4]
//   [1024,3072)   FA2[nn=4][lane=64][8]
//   [3072,5120)   FB2[nn=4][lane=64][8]
//   [5120,9216)   FA3[nn=8][lane=64][8]
//   [9216,13312)  FB3[nn=8][lane=64][8]

// -------- K0: zero cellCnt + cursor ---------------------------------------
__global__ void sa_zero_kernel(int4* __restrict__ dst, int n4) {
    int i = blockIdx.x * blockDim.x + threadIdx.x;
    int stride = gridDim.x * blockDim.x;
    for (; i < n4; i += stride) dst[i] = make_int4(0, 0, 0, 0);
}

// -------- K1: pack pt4, cell ids, cell counts, frag-order f16 weights -----
__global__ void sa_prep_kernel(const float* __restrict__ vtx,
                               float4* __restrict__ pt4,
                               int* __restrict__ cid,
                               int* __restrict__ cellCnt,
                               int N,
                               const float* __restrict__ W1,
                               const float* __restrict__ W2,
                               const float* __restrict__ W3,
                               _Float16* __restrict__ wf16) {
    int i = blockIdx.x * blockDim.x + threadIdx.x;
    int stride = gridDim.x * blockDim.x;
    for (int p = i; p < N; p += stride) {
        float x = vtx[3 * p], y = vtx[3 * p + 1], z = vtx[3 * p + 2];
        float sn = fmaf(z, z, fmaf(y, y, x * x));
        pt4[p] = make_float4(x, y, z, sn);
        int cc = (cellcoord(z) * GD + cellcoord(y)) * GD + cellcoord(x);
        cid[p] = cc;
        atomicAdd(&cellCnt[cc], 1);
    }
    for (int e = i; e < 1024; e += stride) {
        int nn = e >> 8, lane = (e >> 2) & 63, j = e & 3;
        int col = nn * 16 + (lane & 15), k = (lane >> 4) * 4 + j;
        wf16[e] = (k < 6) ? (_Float16)W1[k * 64 + col] : (_Float16)0.f;
    }
    for (int e = i; e < 2048; e += stride) {
        int nn = e >> 9, lane = (e >> 3) & 63, j = e & 7;
        int col = nn * 16 + (lane & 15), k = (lane >> 4) * 8 + j;
        wf16[1024 + e] = (_Float16)W2[k * 64 + col];
        wf16[3072 + e] = (_Float16)W2[(k + 32) * 64 + col];
    }
    for (int e = i; e < 4096; e += stride) {
        int nn = e >> 9, lane = (e >> 3) & 63, j = e & 7;
        int col = nn * 16 + (lane & 15), k = (lane >> 4) * 8 + j;
        wf16[5120 + e] = (_Float16)W3[k * 128 + col];
        wf16[9216 + e] = (_Float16)W3[(k + 32) * 128 + col];
    }
}

// -------- K2: CSR offsets, 250-cell x-row-aligned chunks; also cellEnd ----
__global__ __launch_bounds__(256) void sa_offsets_kernel(
    const int* __restrict__ cellCnt, int* __restrict__ cellStart,
    int* __restrict__ cellEnd, int* __restrict__ cellCur,
    int* __restrict__ cursor) {
    __shared__ int sc[256];
    __shared__ int base_s;
    int t = threadIdx.x;
    int i = blockIdx.x * CHUNK + t;
    int c = (t < CHUNK) ? cellCnt[i] : 0;
    sc[t] = c;
    __syncthreads();
    for (int d = 1; d < 256; d <<= 1) {
        int o = (t >= d) ? sc[t - d] : 0;
        __syncthreads();
        sc[t] += o;
        __syncthreads();
    }
    if (t == 255) base_s = atomicAdd(cursor, sc[255]);
    __syncthreads();
    int start = base_s + sc[t] - c;
    if (t < CHUNK) {
        cellStart[i] = start;
        cellEnd[i] = start + c;
        cellCur[i] = start;
    }
}

// -------- K3: scatter points; also materialize centroid positions ---------
__global__ void sa_scatter_kernel(const float4* __restrict__ pt4,
                                  const int* __restrict__ cid,
                                  int* __restrict__ cellCur,
                                  float4* __restrict__ sorted4,
                                  int* __restrict__ sidx,
                                  const int* __restrict__ cidx,
                                  float4* __restrict__ cpos4,
                                  int N, int M) {
    int p = blockIdx.x * blockDim.x + threadIdx.x;
    if (p < N) {
        int pos = atomicAdd(&cellCur[cid[p]], 1);
        sorted4[pos] = pt4[p];
        sidx[pos] = p;
    }
    if (p < M) cpos4[p] = pt4[cidx[p]];
}

// -------- K4: collect in-radius + top-64 select -> selG/nselG -------------
__global__ __launch_bounds__(64) void sa_collect_kernel(
    const float4* __restrict__ cpos4,
    const float4* __restrict__ sorted4, const int* __restrict__ sidx,
    const int* __restrict__ cellStart, const int* __restrict__ cellEnd,
    int* __restrict__ selG, int* __restrict__ nselG) {

    __shared__ __align__(16) ull key[CAPK + 64];
    __shared__ int selb[64];
    __shared__ int chdesc[64];
    __shared__ int scnt_s;

    int lane = threadIdx.x;
    int c = blockIdx.x;
    float4 cc = cpos4[c];

    int cx = cellcoord(cc.x), cy = cellcoord(cc.y), cz = cellcoord(cc.z);
    int x0 = max(cx - 1, 0), x1 = min(cx + 1, GD - 1), lx = x1 - x0 + 1;
    int y0 = max(cy - 1, 0), y1 = min(cy + 1, GD - 1), ly = y1 - y0 + 1;
    int z0 = max(cz - 1, 0), z1 = min(cz + 1, GD - 1), lz = z1 - z0 + 1;
    int nrow = ly * lz;

    int rstart = 0, rlen = 0;
    if (lane < nrow) {
        int iy = lane % ly, iz = lane / ly;
        int gy = y0 + iy, gz = z0 + iz;
        float ylo = (gy == 0) ? -1e30f : gy * 0.2f - 5.0f;
        float yhi = (gy == GD - 1) ? 1e30f : (gy + 1) * 0.2f - 5.0f;
        float zlo = (gz == 0) ? -1e30f : gz * 0.2f - 5.0f;
        float zhi = (gz == GD - 1) ? 1e30f : (gz + 1) * 0.2f - 5.0f;
        float dy = fmaxf(0.f, fmaxf(ylo - cc.y, cc.y - yhi));
        float dz = fmaxf(0.f, fmaxf(zlo - cc.z, cc.z - zhi));
        if (fmaf(dz, dz, dy * dy) <= R2SAFE) {
            int cell0 = (gz * GD + gy) * GD + x0;
            int cellL = cell0 + (lx - 1);
            rstart = cellStart[cell0];
            rlen = cellEnd[cellL] - rstart;
        }
    }
    if (lane == 0) scnt_s = 0;

    int nch = (rlen + 63) >> 6;
    int ip = nch;
#pragma unroll
    for (int d = 1; d < 16; d <<= 1) {
        int o = __shfl_up(ip, d);
        if (lane >= d) ip += o;
    }
    int C = __shfl(ip, nrow - 1);
    int ebase = ip - nch;
    if (lane < nrow) {
        for (int k = 0; k < nch; ++k) {
            int st = rstart + (k << 6);
            int ln = min(64, rlen - (k << 6));
            chdesc[ebase + k] = st | (ln << 20);
        }
    }

#pragma unroll 2
    for (int ch = 0; ch < C; ++ch) {
        int d0 = chdesc[ch];
        int st = d0 & 0xFFFFF, ln = d0 >> 20;
        if (lane < ln) {
            int sp = st + lane;
            float4 p = sorted4[sp];
            int pid = sidx[sp];
            float dot = fmaf(p.z, cc.z, fmaf(p.y, cc.y, p.x * cc.x));
            float tt = fmaf(-2.f, dot, cc.w) + p.w;
            if (tt <= R2SAFE) {
                float dd = sqrtf(fabsf(tt));
                if (dd <= RADIUS_F) {
                    int slot = atomicAdd(&scnt_s, 1);
                    if (slot < CAPK)
                        key[slot] = (((ull)__float_as_uint(dd)) << 32) | (unsigned)pid;
                }
            }
        }
    }

    int n = min(scnt_s, CAPK);
    int nsel = min(n, 64);
    int n64 = (n + 63) & ~63;
    if (lane < n64 - n) key[n + lane] = ~0ull;
    if (n > 64) {
        for (int i = lane; i < n; i += 64) {
            ull ki = key[i];
            int r = 0;
            for (int j = 0; j < n64; j += 8) {
#pragma unroll
                for (int jj = 0; jj < 8; ++jj)
                    r += (key[j + jj] < ki) ? 1 : 0;
            }
            if (r < 64) selb[r] = (int)(unsigned)(ki & 0xffffffffu);
        }
    } else {
        for (int i = lane; i < n; i += 64)
            selb[i] = (int)(unsigned)(key[i] & 0xffffffffu);
    }

    if (lane < nsel) selG[(size_t)c * 64 + lane] = selb[lane];
    if (lane == 0) nselG[c] = nsel;
}

// -------- K5: 4-wave cooperative MLP, 1 centroid/block --------------------
// Wave w owns cols nn=w (L1,L2) and nn in {2w,2w+1} (L3). Per-wave weight
// slices (~28 VGPR) from L2-hot frag-order wf16. LDS ~10.25KB.
__global__ __launch_bounds__(256) void sa_mlp4_kernel(
    const float4* __restrict__ pt4, const float4* __restrict__ cpos4,
    const int* __restrict__ selG, const int* __restrict__ nselG,
    const _Float16* __restrict__ wf16,
    const float* __restrict__ b1, const float* __restrict__ b2,
    const float* __restrict__ b3, float* __restrict__ out) {

    __shared__ __align__(16) _Float16 featb[1024];   // [64][16]
    __shared__ __align__(16) _Float16 h[4096];       // [64][64] swizzled

    int t = threadIdx.x, w = t >> 6, lane = t & 63;
    int r16 = lane & 15, g = lane >> 4;
    int c = blockIdx.x;
    int nsel = nselG[c];
    float4 cc = cpos4[c];

    // per-wave weight slices -> registers (coalesced, L2-hot, loaded once)
    f16x4 F1  = ((const f16x4*)wf16)[w * 64 + lane];
    f16x8 FA2 = ((const f16x8*)(wf16 + 1024))[w * 64 + lane];
    f16x8 FB2 = ((const f16x8*)(wf16 + 3072))[w * 64 + lane];
    f16x8 FA3a = ((const f16x8*)(wf16 + 5120))[(2 * w + 0) * 64 + lane];
    f16x8 FA3b = ((const f16x8*)(wf16 + 5120))[(2 * w + 1) * 64 + lane];
    f16x8 FB3a = ((const f16x8*)(wf16 + 9216))[(2 * w + 0) * 64 + lane];
    f16x8 FB3b = ((const f16x8*)(wf16 + 9216))[(2 * w + 1) * 64 + lane];
    float B1 = b1[w * 16 + r16];
    float B2 = b2[w * 16 + r16];
    float B3a = b3[(2 * w + 0) * 16 + r16];
    float B3b = b3[(2 * w + 1) * 16 + r16];

    // gather feats (first 64 threads, one row each)
    if (t < 64) {
        _Float16 z = (_Float16)0.f;
        f16x8 lo8 = {z, z, z, z, z, z, z, z};
        if (t < nsel) {
            float4 p = pt4[selG[(size_t)c * 64 + t]];
            lo8[0] = (_Float16)p.x; lo8[1] = (_Float16)p.y; lo8[2] = (_Float16)p.z;
            lo8[3] = (_Float16)(p.x - cc.x);
            lo8[4] = (_Float16)(p.y - cc.y);
            lo8[5] = (_Float16)(p.z - cc.z);
        }
        f16x8 hi8 = {z, z, z, z, z, z, z, z};
        *(f16x8*)&featb[t * 16 + 0] = lo8;
        *(f16x8*)&featb[t * 16 + 8] = hi8;
    }
    __syncthreads();

    // ---- L1: wave w -> cols w*16..w*16+15; writes h ----
    {
        f16x4 a1[4];
#pragma unroll
        for (int m = 0; m < 4; ++m)
            a1[m] = *(const f16x4*)&featb[(m * 16 + r16) * 16 + g * 4];
        int col = w * 16 + r16;
#pragma unroll
        for (int m = 0; m < 4; ++m) {
            f32x4 acc = {B1, B1, B1, B1};
            acc = __builtin_amdgcn_mfma_f32_16x16x16f16(a1[m], F1, acc, 0, 0, 0);
#pragma unroll
            for (int reg = 0; reg < 4; ++reg) {
                int row = m * 16 + g * 4 + reg;
                h[row * 64 + (col ^ ((row & 7) << 3))] =
                    (_Float16)fmaxf(acc[reg], 0.f);
            }
        }
    }
    __syncthreads();

    // ---- L2: preload full-row A frags, barrier, then write own col slice --
    {
        f16x8 a2[4][2];
#pragma unroll
        for (int m = 0; m < 4; ++m)
#pragma unroll
            for (int kt = 0; kt < 2; ++kt) {
                int row = m * 16 + r16;
                int k0 = kt * 32 + g * 8;
                a2[m][kt] = *(const f16x8*)&h[row * 64 + (k0 ^ ((row & 7) << 3))];
            }
        __syncthreads();                 // all preloads done before overwrite
        int col = w * 16 + r16;
#pragma unroll
        for (int m = 0; m < 4; ++m) {
            f32x4 acc = {B2, B2, B2, B2};
            acc = __builtin_amdgcn_mfma_f32_16x16x32_f16(a2[m][0], FA2, acc, 0, 0, 0);
            acc = __builtin_amdgcn_mfma_f32_16x16x32_f16(a2[m][1], FB2, acc, 0, 0, 0);
#pragma unroll
            for (int reg = 0; reg < 4; ++reg) {
                int row = m * 16 + g * 4 + reg;
                h[row * 64 + (col ^ ((row & 7) << 3))] =
                    (_Float16)fmaxf(acc[reg], 0.f);
            }
        }
    }
    __syncthreads();

    // ---- L3: wave w -> cols (2w..2w+1)*16; masked max over rows ----
    {
        f16x8 a3[4][2];
#pragma unroll
        for (int m = 0; m < 4; ++m)
#pragma unroll
            for (int kt = 0; kt < 2; ++kt) {
                int row = m * 16 + r16;
                int k0 = kt * 32 + g * 8;
                a3[m][kt] = *(const f16x8*)&h[row * 64 + (k0 ^ ((row & 7) << 3))];
            }
        float ninf = __int_as_float(0xff800000);
#pragma unroll
        for (int q = 0; q < 2; ++q) {
            float bb = q ? B3b : B3a;
            f16x8 fa = q ? FA3b : FA3a;
            f16x8 fb = q ? FB3b : FB3a;
            float vm = ninf;
#pragma unroll
            for (int m = 0; m < 4; ++m) {
                f32x4 acc = {bb, bb, bb, bb};
                acc = __builtin_amdgcn_mfma_f32_16x16x32_f16(a3[m][0], fa, acc, 0, 0, 0);
                acc = __builtin_amdgcn_mfma_f32_16x16x32_f16(a3[m][1], fb, acc, 0, 0, 0);
#pragma unroll
                for (int reg = 0; reg < 4; ++reg) {
                    int row = m * 16 + g * 4 + reg;
                    if (row < nsel) vm = fmaxf(vm, acc[reg]);
                }
            }
            vm = fmaxf(vm, __shfl_xor(vm, 16));
            vm = fmaxf(vm, __shfl_xor(vm, 32));
            if (lane < 16)
                out[(size_t)c * 128 + (2 * w + q) * 16 + lane] = vm;
        }
    }
}

extern "C" void kernel_launch(void* const* d_in, const int* in_sizes, int n_in,
                              void* d_out, int out_size, void* d_ws, size_t ws_size,
                              hipStream_t stream) {
    const float* vtx = (const float*)d_in[0];
    const int* cidx  = (const int*)d_in[1];
    const float* W1  = (const float*)d_in[2];
    const float* b1  = (const float*)d_in[3];
    const float* W2  = (const float*)d_in[4];
    const float* b2  = (const float*)d_in[5];
    const float* W3  = (const float*)d_in[6];
    const float* b3  = (const float*)d_in[7];
    float* out = (float*)d_out;

    int N = in_sizes[0] / 3;   // 65536
    int M = in_sizes[1];       // 4096

    char* ws = (char*)d_ws;
    size_t off = 0;
    float4* pt4     = (float4*)(ws + off); off += (size_t)N * 16;
    float4* sorted4 = (float4*)(ws + off); off += (size_t)N * 16;
    float4* cpos4   = (float4*)(ws + off); off += (size_t)M * 16;
    int* sidx       = (int*)(ws + off);    off += (size_t)N * 4;
    int* cid        = (int*)(ws + off);    off += (size_t)N * 4;
    int* cellCnt    = (int*)(ws + off);    off += (size_t)NC * 4;
    int* cursor     = (int*)(ws + off);    off += 16;
    int* cellStart  = (int*)(ws + off);    off += (size_t)NC * 4;
    int* cellEnd    = (int*)(ws + off);    off += (size_t)NC * 4;
    int* cellCur    = (int*)(ws + off);    off += (size_t)NC * 4;
    int* selG       = (int*)(ws + off);    off += (size_t)M * 64 * 4;
    int* nselG      = (int*)(ws + off);    off += (size_t)M * 4;
    _Float16* wf16  = (_Float16*)(ws + off);

    sa_zero_kernel<<<256, 256, 0, stream>>>((int4*)cellCnt, (NC * 4 + 16) / 16);
    sa_prep_kernel<<<512, 256, 0, stream>>>(vtx, pt4, cid, cellCnt, N,
                                            W1, W2, W3, wf16);
    sa_offsets_kernel<<<NC / CHUNK, 256, 0, stream>>>(cellCnt, cellStart,
                                                      cellEnd, cellCur, cursor);
    sa_scatter_kernel<<<(N + 255) / 256, 256, 0, stream>>>(pt4, cid, cellCur,
                                                           sorted4, sidx,
                                                           cidx, cpos4, N, M);
    sa_collect_kernel<<<M, 64, 0, stream>>>(cpos4, sorted4, sidx,
                                            cellStart, cellEnd, selG, nselG);
    sa_mlp4_kernel<<<M, 256, 0, stream>>>(pt4, cpos4, selG, nselG, wf16,
                                          b1, b2, b3, out);
}

// Round 18
// 66.444 us; speedup vs baseline: 1.1928x; 1.0298x over previous
//
#include <hip/hip_runtime.h>
#include <hip/hip_bf16.h>

#define GD     50          // grid cells per dim
#define NC     (GD*GD*GD)  // 125000
#define CHUNK  250         // cells per offsets block; 250%50==0 keeps x-rows intact
#define CAPK   256         // in-radius candidate capacity per centroid
#define RADIUS_F 0.2f
#define R2SAFE 0.0401f

typedef unsigned long long ull;
typedef __attribute__((ext_vector_type(4))) _Float16 f16x4;
typedef __attribute__((ext_vector_type(8))) _Float16 f16x8;
typedef __attribute__((ext_vector_type(4))) float    f32x4;

__device__ __forceinline__ int cellcoord(float v) {
    int c = (int)floorf((v + 5.0f) * 5.0f);
    return min(max(c, 0), GD - 1);
}

// Fragment-order weight layout in wf16 (13312 f16):
//   [0,1024)      F1 [nn=4][lane=64][4]
//   [1024,3072)   FA2[nn=4][lane=64][8]
//   [3072,5120)   FB2[nn=4][lane=64][8]
//   [5120,9216)   FA3[nn=8][lane=64][8]
//   [9216,13312)  FB3[nn=8][lane=64][8]

// -------- K0: zero cellCnt + cursor ---------------------------------------
__global__ void sa_zero_kernel(int4* __restrict__ dst, int n4) {
    int i = blockIdx.x * blockDim.x + threadIdx.x;
    int stride = gridDim.x * blockDim.x;
    for (; i < n4; i += stride) dst[i] = make_int4(0, 0, 0, 0);
}

// -------- K1: pack pt4, cell ids, cell counts, frag-order f16 weights -----
__global__ void sa_prep_kernel(const float* __restrict__ vtx,
                               float4* __restrict__ pt4,
                               int* __restrict__ cid,
                               int* __restrict__ cellCnt,
                               int N,
                               const float* __restrict__ W1,
                               const float* __restrict__ W2,
                               const float* __restrict__ W3,
                               _Float16* __restrict__ wf16) {
    int i = blockIdx.x * blockDim.x + threadIdx.x;
    int stride = gridDim.x * blockDim.x;
    for (int p = i; p < N; p += stride) {
        float x = vtx[3 * p], y = vtx[3 * p + 1], z = vtx[3 * p + 2];
        float sn = fmaf(z, z, fmaf(y, y, x * x));
        pt4[p] = make_float4(x, y, z, sn);
        int cc = (cellcoord(z) * GD + cellcoord(y)) * GD + cellcoord(x);
        cid[p] = cc;
        atomicAdd(&cellCnt[cc], 1);
    }
    for (int e = i; e < 1024; e += stride) {
        int nn = e >> 8, lane = (e >> 2) & 63, j = e & 3;
        int col = nn * 16 + (lane & 15), k = (lane >> 4) * 4 + j;
        wf16[e] = (k < 6) ? (_Float16)W1[k * 64 + col] : (_Float16)0.f;
    }
    for (int e = i; e < 2048; e += stride) {
        int nn = e >> 9, lane = (e >> 3) & 63, j = e & 7;
        int col = nn * 16 + (lane & 15), k = (lane >> 4) * 8 + j;
        wf16[1024 + e] = (_Float16)W2[k * 64 + col];
        wf16[3072 + e] = (_Float16)W2[(k + 32) * 64 + col];
    }
    for (int e = i; e < 4096; e += stride) {
        int nn = e >> 9, lane = (e >> 3) & 63, j = e & 7;
        int col = nn * 16 + (lane & 15), k = (lane >> 4) * 8 + j;
        wf16[5120 + e] = (_Float16)W3[k * 128 + col];
        wf16[9216 + e] = (_Float16)W3[(k + 32) * 128 + col];
    }
}

// -------- K2: CSR offsets, 250-cell x-row-aligned chunks; also cellEnd ----
__global__ __launch_bounds__(256) void sa_offsets_kernel(
    const int* __restrict__ cellCnt, int* __restrict__ cellStart,
    int* __restrict__ cellEnd, int* __restrict__ cellCur,
    int* __restrict__ cursor) {
    __shared__ int sc[256];
    __shared__ int base_s;
    int t = threadIdx.x;
    int i = blockIdx.x * CHUNK + t;
    int c = (t < CHUNK) ? cellCnt[i] : 0;
    sc[t] = c;
    __syncthreads();
    for (int d = 1; d < 256; d <<= 1) {
        int o = (t >= d) ? sc[t - d] : 0;
        __syncthreads();
        sc[t] += o;
        __syncthreads();
    }
    if (t == 255) base_s = atomicAdd(cursor, sc[255]);
    __syncthreads();
    int start = base_s + sc[t] - c;
    if (t < CHUNK) {
        cellStart[i] = start;
        cellEnd[i] = start + c;
        cellCur[i] = start;
    }
}

// -------- K3: scatter points; also materialize centroid positions ---------
__global__ void sa_scatter_kernel(const float4* __restrict__ pt4,
                                  const int* __restrict__ cid,
                                  int* __restrict__ cellCur,
                                  float4* __restrict__ sorted4,
                                  int* __restrict__ sidx,
                                  const int* __restrict__ cidx,
                                  float4* __restrict__ cpos4,
                                  int N, int M) {
    int p = blockIdx.x * blockDim.x + threadIdx.x;
    if (p < N) {
        int pos = atomicAdd(&cellCur[cid[p]], 1);
        sorted4[pos] = pt4[p];
        sidx[pos] = p;
    }
    if (p < M) cpos4[p] = pt4[cidx[p]];
}

// -------- K4: collect + top-64 + emit dense f16 feature rows --------------
// Positions carried through LDS (pos_s) -- no pt4 re-gather.
__global__ __launch_bounds__(64) void sa_collect_kernel(
    const float4* __restrict__ cpos4,
    const float4* __restrict__ sorted4, const int* __restrict__ sidx,
    const int* __restrict__ cellStart, const int* __restrict__ cellEnd,
    _Float16* __restrict__ featG, int* __restrict__ nselG) {

    __shared__ __align__(16) ull key[CAPK + 64];
    __shared__ __align__(16) float4 pos_s[CAPK];
    __shared__ int selb[64];
    __shared__ int chdesc[64];
    __shared__ int scnt_s;

    int lane = threadIdx.x;
    int c = blockIdx.x;
    float4 cc = cpos4[c];

    int cx = cellcoord(cc.x), cy = cellcoord(cc.y), cz = cellcoord(cc.z);
    int x0 = max(cx - 1, 0), x1 = min(cx + 1, GD - 1), lx = x1 - x0 + 1;
    int y0 = max(cy - 1, 0), y1 = min(cy + 1, GD - 1), ly = y1 - y0 + 1;
    int z0 = max(cz - 1, 0), z1 = min(cz + 1, GD - 1), lz = z1 - z0 + 1;
    int nrow = ly * lz;

    int rstart = 0, rlen = 0;
    if (lane < nrow) {
        int iy = lane % ly, iz = lane / ly;
        int gy = y0 + iy, gz = z0 + iz;
        float ylo = (gy == 0) ? -1e30f : gy * 0.2f - 5.0f;
        float yhi = (gy == GD - 1) ? 1e30f : (gy + 1) * 0.2f - 5.0f;
        float zlo = (gz == 0) ? -1e30f : gz * 0.2f - 5.0f;
        float zhi = (gz == GD - 1) ? 1e30f : (gz + 1) * 0.2f - 5.0f;
        float dy = fmaxf(0.f, fmaxf(ylo - cc.y, cc.y - yhi));
        float dz = fmaxf(0.f, fmaxf(zlo - cc.z, cc.z - zhi));
        if (fmaf(dz, dz, dy * dy) <= R2SAFE) {
            int cell0 = (gz * GD + gy) * GD + x0;
            int cellL = cell0 + (lx - 1);
            rstart = cellStart[cell0];
            rlen = cellEnd[cellL] - rstart;
        }
    }
    if (lane == 0) scnt_s = 0;

    int nch = (rlen + 63) >> 6;
    int ip = nch;
#pragma unroll
    for (int d = 1; d < 16; d <<= 1) {
        int o = __shfl_up(ip, d);
        if (lane >= d) ip += o;
    }
    int C = __shfl(ip, nrow - 1);
    int ebase = ip - nch;
    if (lane < nrow) {
        for (int k = 0; k < nch; ++k) {
            int st = rstart + (k << 6);
            int ln = min(64, rlen - (k << 6));
            chdesc[ebase + k] = st | (ln << 20);
        }
    }

#pragma unroll 2
    for (int ch = 0; ch < C; ++ch) {
        int d0 = chdesc[ch];
        int st = d0 & 0xFFFFF, ln = d0 >> 20;
        if (lane < ln) {
            int sp = st + lane;
            float4 p = sorted4[sp];
            int pid = sidx[sp];
            float dot = fmaf(p.z, cc.z, fmaf(p.y, cc.y, p.x * cc.x));
            float tt = fmaf(-2.f, dot, cc.w) + p.w;
            if (tt <= R2SAFE) {
                float dd = sqrtf(fabsf(tt));
                if (dd <= RADIUS_F) {
                    int slot = atomicAdd(&scnt_s, 1);
                    if (slot < CAPK) {
                        key[slot] = (((ull)__float_as_uint(dd)) << 32) | (unsigned)pid;
                        pos_s[slot] = p;
                    }
                }
            }
        }
    }

    // top-64 by (d_bits, idx); selb stores SLOT index
    int n = min(scnt_s, CAPK);
    int nsel = min(n, 64);
    int n64 = (n + 63) & ~63;
    if (lane < n64 - n) key[n + lane] = ~0ull;
    if (n > 64) {
        for (int i = lane; i < n; i += 64) {
            ull ki = key[i];
            int r = 0;
            for (int j = 0; j < n64; j += 8) {
#pragma unroll
                for (int jj = 0; jj < 8; ++jj)
                    r += (key[j + jj] < ki) ? 1 : 0;
            }
            if (r < 64) selb[r] = i;
        }
    } else {
        for (int i = lane; i < n; i += 64) selb[i] = i;
    }

    // emit dense f16 feature rows [64][16], zero-padded (from LDS pos)
    {
        _Float16 z = (_Float16)0.f;
        f16x8 lo8 = {z, z, z, z, z, z, z, z};
        if (lane < nsel) {
            float4 p = pos_s[selb[lane]];
            lo8[0] = (_Float16)p.x; lo8[1] = (_Float16)p.y; lo8[2] = (_Float16)p.z;
            lo8[3] = (_Float16)(p.x - cc.x);
            lo8[4] = (_Float16)(p.y - cc.y);
            lo8[5] = (_Float16)(p.z - cc.z);
        }
        f16x8 hi8 = {z, z, z, z, z, z, z, z};
        _Float16* fr = featG + (size_t)c * 1024 + lane * 16;
        *(f16x8*)(fr + 0) = lo8;
        *(f16x8*)(fr + 8) = hi8;
    }
    if (lane == 0) nselG[c] = nsel;
}

// -------- K5: 4-wave cooperative MLP, A-frags straight from featG ---------
// Wave w owns cols nn=w (L1,L2) and nn in {2w,2w+1} (L3). LDS 8KB (h only).
__global__ __launch_bounds__(256) void sa_mlp4_kernel(
    const _Float16* __restrict__ featG, const int* __restrict__ nselG,
    const _Float16* __restrict__ wf16,
    const float* __restrict__ b1, const float* __restrict__ b2,
    const float* __restrict__ b3, float* __restrict__ out) {

    __shared__ __align__(16) _Float16 h[4096];       // [64][64] swizzled

    int t = threadIdx.x, w = t >> 6, lane = t & 63;
    int r16 = lane & 15, g = lane >> 4;
    int c = blockIdx.x;
    int nsel = nselG[c];
    const _Float16* fG = featG + (size_t)c * 1024;

    // per-wave weight slices -> registers (coalesced, L2-hot, loaded once)
    f16x4 F1  = ((const f16x4*)wf16)[w * 64 + lane];
    f16x8 FA2 = ((const f16x8*)(wf16 + 1024))[w * 64 + lane];
    f16x8 FB2 = ((const f16x8*)(wf16 + 3072))[w * 64 + lane];
    f16x8 FA3a = ((const f16x8*)(wf16 + 5120))[(2 * w + 0) * 64 + lane];
    f16x8 FA3b = ((const f16x8*)(wf16 + 5120))[(2 * w + 1) * 64 + lane];
    f16x8 FB3a = ((const f16x8*)(wf16 + 9216))[(2 * w + 0) * 64 + lane];
    f16x8 FB3b = ((const f16x8*)(wf16 + 9216))[(2 * w + 1) * 64 + lane];
    float B1 = b1[w * 16 + r16];
    float B2 = b2[w * 16 + r16];
    float B3a = b3[(2 * w + 0) * 16 + r16];
    float B3b = b3[(2 * w + 1) * 16 + r16];

    // ---- L1: A-frags straight from featG (coalesced 512B/wave-load) ----
    {
        f16x4 a1[4];
#pragma unroll
        for (int m = 0; m < 4; ++m)
            a1[m] = *(const f16x4*)&fG[(m * 16 + r16) * 16 + g * 4];
        int col = w * 16 + r16;
#pragma unroll
        for (int m = 0; m < 4; ++m) {
            f32x4 acc = {B1, B1, B1, B1};
            acc = __builtin_amdgcn_mfma_f32_16x16x16f16(a1[m], F1, acc, 0, 0, 0);
#pragma unroll
            for (int reg = 0; reg < 4; ++reg) {
                int row = m * 16 + g * 4 + reg;
                h[row * 64 + (col ^ ((row & 7) << 3))] =
                    (_Float16)fmaxf(acc[reg], 0.f);
            }
        }
    }
    __syncthreads();

    // ---- L2: preload full-row A frags, barrier, write own col slice ----
    {
        f16x8 a2[4][2];
#pragma unroll
        for (int m = 0; m < 4; ++m)
#pragma unroll
            for (int kt = 0; kt < 2; ++kt) {
                int row = m * 16 + r16;
                int k0 = kt * 32 + g * 8;
                a2[m][kt] = *(const f16x8*)&h[row * 64 + (k0 ^ ((row & 7) << 3))];
            }
        __syncthreads();
        int col = w * 16 + r16;
#pragma unroll
        for (int m = 0; m < 4; ++m) {
            f32x4 acc = {B2, B2, B2, B2};
            acc = __builtin_amdgcn_mfma_f32_16x16x32_f16(a2[m][0], FA2, acc, 0, 0, 0);
            acc = __builtin_amdgcn_mfma_f32_16x16x32_f16(a2[m][1], FB2, acc, 0, 0, 0);
#pragma unroll
            for (int reg = 0; reg < 4; ++reg) {
                int row = m * 16 + g * 4 + reg;
                h[row * 64 + (col ^ ((row & 7) << 3))] =
                    (_Float16)fmaxf(acc[reg], 0.f);
            }
        }
    }
    __syncthreads();

    // ---- L3: wave w -> cols (2w..2w+1)*16; masked max over rows ----
    {
        f16x8 a3[4][2];
#pragma unroll
        for (int m = 0; m < 4; ++m)
#pragma unroll
            for (int kt = 0; kt < 2; ++kt) {
                int row = m * 16 + r16;
                int k0 = kt * 32 + g * 8;
                a3[m][kt] = *(const f16x8*)&h[row * 64 + (k0 ^ ((row & 7) << 3))];
            }
        float ninf = __int_as_float(0xff800000);
#pragma unroll
        for (int q = 0; q < 2; ++q) {
            float bb = q ? B3b : B3a;
            f16x8 fa = q ? FA3b : FA3a;
            f16x8 fb = q ? FB3b : FB3a;
            float vm = ninf;
#pragma unroll
            for (int m = 0; m < 4; ++m) {
                f32x4 acc = {bb, bb, bb, bb};
                acc = __builtin_amdgcn_mfma_f32_16x16x32_f16(a3[m][0], fa, acc, 0, 0, 0);
                acc = __builtin_amdgcn_mfma_f32_16x16x32_f16(a3[m][1], fb, acc, 0, 0, 0);
#pragma unroll
                for (int reg = 0; reg < 4; ++reg) {
                    int row = m * 16 + g * 4 + reg;
                    if (row < nsel) vm = fmaxf(vm, acc[reg]);
                }
            }
            vm = fmaxf(vm, __shfl_xor(vm, 16));
            vm = fmaxf(vm, __shfl_xor(vm, 32));
            if (lane < 16)
                out[(size_t)c * 128 + (2 * w + q) * 16 + lane] = vm;
        }
    }
}

extern "C" void kernel_launch(void* const* d_in, const int* in_sizes, int n_in,
                              void* d_out, int out_size, void* d_ws, size_t ws_size,
                              hipStream_t stream) {
    const float* vtx = (const float*)d_in[0];
    const int* cidx  = (const int*)d_in[1];
    const float* W1  = (const float*)d_in[2];
    const float* b1  = (const float*)d_in[3];
    const float* W2  = (const float*)d_in[4];
    const float* b2  = (const float*)d_in[5];
    const float* W3  = (const float*)d_in[6];
    const float* b3  = (const float*)d_in[7];
    float* out = (float*)d_out;

    int N = in_sizes[0] / 3;   // 65536
    int M = in_sizes[1];       // 4096

    char* ws = (char*)d_ws;
    size_t off = 0;
    float4* pt4     = (float4*)(ws + off); off += (size_t)N * 16;
    float4* sorted4 = (float4*)(ws + off); off += (size_t)N * 16;
    float4* cpos4   = (float4*)(ws + off); off += (size_t)M * 16;
    int* sidx       = (int*)(ws + off);    off += (size_t)N * 4;
    int* cid        = (int*)(ws + off);    off += (size_t)N * 4;
    int* cellCnt    = (int*)(ws + off);    off += (size_t)NC * 4;
    int* cursor     = (int*)(ws + off);    off += 16;
    int* cellStart  = (int*)(ws + off);    off += (size_t)NC * 4;
    int* cellEnd    = (int*)(ws + off);    off += (size_t)NC * 4;
    int* cellCur    = (int*)(ws + off);    off += (size_t)NC * 4;
    _Float16* featG = (_Float16*)(ws + off); off += (size_t)M * 1024 * 2;
    int* nselG      = (int*)(ws + off);    off += (size_t)M * 4;
    _Float16* wf16  = (_Float16*)(ws + off);

    sa_zero_kernel<<<256, 256, 0, stream>>>((int4*)cellCnt, (NC * 4 + 16) / 16);
    sa_prep_kernel<<<512, 256, 0, stream>>>(vtx, pt4, cid, cellCnt, N,
                                            W1, W2, W3, wf16);
    sa_offsets_kernel<<<NC / CHUNK, 256, 0, stream>>>(cellCnt, cellStart,
                                                      cellEnd, cellCur, cursor);
    sa_scatter_kernel<<<(N + 255) / 256, 256, 0, stream>>>(pt4, cid, cellCur,
                                                           sorted4, sidx,
                                                           cidx, cpos4, N, M);
    sa_collect_kernel<<<M, 64, 0, stream>>>(cpos4, sorted4, sidx,
                                            cellStart, cellEnd, featG, nselG);
    sa_mlp4_kernel<<<M, 256, 0, stream>>>(featG, nselG, wf16,
                                          b1, b2, b3, out);
}

// Round 19
// 64.549 us; speedup vs baseline: 1.2279x; 1.0294x over previous
//
#include <hip/hip_runtime.h>
#include <hip/hip_bf16.h>

#define GD     50          // grid cells per dim
#define NC     (GD*GD*GD)  // 125000
#define CHUNK  250         // cells per offsets block; 250%50==0 keeps x-rows intact
#define CAPK   256         // in-radius candidate capacity per centroid
#define RADIUS_F 0.2f
#define R2SAFE 0.0401f

typedef unsigned long long ull;
typedef __attribute__((ext_vector_type(4))) _Float16 f16x4;
typedef __attribute__((ext_vector_type(8))) _Float16 f16x8;
typedef __attribute__((ext_vector_type(4))) float    f32x4;

__device__ __forceinline__ int cellcoord(float v) {
    int c = (int)floorf((v + 5.0f) * 5.0f);
    return min(max(c, 0), GD - 1);
}

// Fragment-order weight layout in wf16 (13312 f16):
//   [0,1024)      F1 [nn=4][lane=64][4]
//   [1024,3072)   FA2[nn=4][lane=64][8]
//   [3072,5120)   FB2[nn=4][lane=64][8]
//   [5120,9216)   FA3[nn=8][lane=64][8]
//   [9216,13312)  FB3[nn=8][lane=64][8]

// -------- K0: zero cellCnt + cursor ---------------------------------------
__global__ void sa_zero_kernel(int4* __restrict__ dst, int n4) {
    int i = blockIdx.x * blockDim.x + threadIdx.x;
    int stride = gridDim.x * blockDim.x;
    for (; i < n4; i += stride) dst[i] = make_int4(0, 0, 0, 0);
}

// -------- K1: count cells + frag-order f16 weights ------------------------
__global__ void sa_count_kernel(const float* __restrict__ vtx,
                                int* __restrict__ cellCnt, int N,
                                const float* __restrict__ W1,
                                const float* __restrict__ W2,
                                const float* __restrict__ W3,
                                _Float16* __restrict__ wf16) {
    int i = blockIdx.x * blockDim.x + threadIdx.x;
    int stride = gridDim.x * blockDim.x;
    for (int p = i; p < N; p += stride) {
        float x = vtx[3 * p], y = vtx[3 * p + 1], z = vtx[3 * p + 2];
        int cc = (cellcoord(z) * GD + cellcoord(y)) * GD + cellcoord(x);
        atomicAdd(&cellCnt[cc], 1);
    }
    for (int e = i; e < 1024; e += stride) {
        int nn = e >> 8, lane = (e >> 2) & 63, j = e & 3;
        int col = nn * 16 + (lane & 15), k = (lane >> 4) * 4 + j;
        wf16[e] = (k < 6) ? (_Float16)W1[k * 64 + col] : (_Float16)0.f;
    }
    for (int e = i; e < 2048; e += stride) {
        int nn = e >> 9, lane = (e >> 3) & 63, j = e & 7;
        int col = nn * 16 + (lane & 15), k = (lane >> 4) * 8 + j;
        wf16[1024 + e] = (_Float16)W2[k * 64 + col];
        wf16[3072 + e] = (_Float16)W2[(k + 32) * 64 + col];
    }
    for (int e = i; e < 4096; e += stride) {
        int nn = e >> 9, lane = (e >> 3) & 63, j = e & 7;
        int col = nn * 16 + (lane & 15), k = (lane >> 4) * 8 + j;
        wf16[5120 + e] = (_Float16)W3[k * 128 + col];
        wf16[9216 + e] = (_Float16)W3[(k + 32) * 128 + col];
    }
}

// -------- K2: CSR offsets, 250-cell x-row-aligned chunks; also cellEnd ----
__global__ __launch_bounds__(256) void sa_offsets_kernel(
    const int* __restrict__ cellCnt, int* __restrict__ cellStart,
    int* __restrict__ cellEnd, int* __restrict__ cellCur,
    int* __restrict__ cursor) {
    __shared__ int sc[256];
    __shared__ int base_s;
    int t = threadIdx.x;
    int i = blockIdx.x * CHUNK + t;
    int c = (t < CHUNK) ? cellCnt[i] : 0;
    sc[t] = c;
    __syncthreads();
    for (int d = 1; d < 256; d <<= 1) {
        int o = (t >= d) ? sc[t - d] : 0;
        __syncthreads();
        sc[t] += o;
        __syncthreads();
    }
    if (t == 255) base_s = atomicAdd(cursor, sc[255]);
    __syncthreads();
    int start = base_s + sc[t] - c;
    if (t < CHUNK) {
        cellStart[i] = start;
        cellEnd[i] = start + c;
        cellCur[i] = start;
    }
}

// -------- K3: scatter points (pid packed in w); build cpos4 ---------------
__global__ void sa_scatter_kernel(const float* __restrict__ vtx,
                                  int* __restrict__ cellCur,
                                  float4* __restrict__ sorted4,
                                  const int* __restrict__ cidx,
                                  float4* __restrict__ cpos4,
                                  int N, int M) {
    int p = blockIdx.x * blockDim.x + threadIdx.x;
    if (p < N) {
        float x = vtx[3 * p], y = vtx[3 * p + 1], z = vtx[3 * p + 2];
        int cc = (cellcoord(z) * GD + cellcoord(y)) * GD + cellcoord(x);
        int pos = atomicAdd(&cellCur[cc], 1);
        sorted4[pos] = make_float4(x, y, z, __int_as_float(p));
    }
    if (p < M) {
        int i = cidx[p];
        float x = vtx[3 * i], y = vtx[3 * i + 1], z = vtx[3 * i + 2];
        float sn = fmaf(z, z, fmaf(y, y, x * x));
        cpos4[p] = make_float4(x, y, z, sn);
    }
}

// -------- K4: collect + top-64 + emit dense f16 feature rows --------------
__global__ __launch_bounds__(64) void sa_collect_kernel(
    const float4* __restrict__ cpos4,
    const float4* __restrict__ sorted4,
    const int* __restrict__ cellStart, const int* __restrict__ cellEnd,
    _Float16* __restrict__ featG, int* __restrict__ nselG) {

    __shared__ __align__(16) ull key[CAPK + 64];
    __shared__ __align__(16) float4 pos_s[CAPK];
    __shared__ int selb[64];
    __shared__ int chdesc[64];
    __shared__ int scnt_s;

    int lane = threadIdx.x;
    int c = blockIdx.x;
    float4 cc = cpos4[c];

    int cx = cellcoord(cc.x), cy = cellcoord(cc.y), cz = cellcoord(cc.z);
    int x0 = max(cx - 1, 0), x1 = min(cx + 1, GD - 1), lx = x1 - x0 + 1;
    int y0 = max(cy - 1, 0), y1 = min(cy + 1, GD - 1), ly = y1 - y0 + 1;
    int z0 = max(cz - 1, 0), z1 = min(cz + 1, GD - 1), lz = z1 - z0 + 1;
    int nrow = ly * lz;

    int rstart = 0, rlen = 0;
    if (lane < nrow) {
        int iy = lane % ly, iz = lane / ly;
        int gy = y0 + iy, gz = z0 + iz;
        float ylo = (gy == 0) ? -1e30f : gy * 0.2f - 5.0f;
        float yhi = (gy == GD - 1) ? 1e30f : (gy + 1) * 0.2f - 5.0f;
        float zlo = (gz == 0) ? -1e30f : gz * 0.2f - 5.0f;
        float zhi = (gz == GD - 1) ? 1e30f : (gz + 1) * 0.2f - 5.0f;
        float dy = fmaxf(0.f, fmaxf(ylo - cc.y, cc.y - yhi));
        float dz = fmaxf(0.f, fmaxf(zlo - cc.z, cc.z - zhi));
        if (fmaf(dz, dz, dy * dy) <= R2SAFE) {
            int cell0 = (gz * GD + gy) * GD + x0;
            int cellL = cell0 + (lx - 1);
            rstart = cellStart[cell0];
            rlen = cellEnd[cellL] - rstart;
        }
    }
    if (lane == 0) scnt_s = 0;

    int nch = (rlen + 63) >> 6;
    int ip = nch;
#pragma unroll
    for (int d = 1; d < 16; d <<= 1) {
        int o = __shfl_up(ip, d);
        if (lane >= d) ip += o;
    }
    int C = __shfl(ip, nrow - 1);
    int ebase = ip - nch;
    if (lane < nrow) {
        for (int k = 0; k < nch; ++k) {
            int st = rstart + (k << 6);
            int ln = min(64, rlen - (k << 6));
            chdesc[ebase + k] = st | (ln << 20);
        }
    }

#pragma unroll 2
    for (int ch = 0; ch < C; ++ch) {
        int d0 = chdesc[ch];
        int st = d0 & 0xFFFFF, ln = d0 >> 20;
        if (lane < ln) {
            int sp = st + lane;
            float4 p = sorted4[sp];
            // sn recomputed with the SAME fma chain as cpos4 build (bit-exact)
            float psn = fmaf(p.z, p.z, fmaf(p.y, p.y, p.x * p.x));
            float dot = fmaf(p.z, cc.z, fmaf(p.y, cc.y, p.x * cc.x));
            float tt = fmaf(-2.f, dot, cc.w) + psn;
            if (tt <= R2SAFE) {
                float dd = sqrtf(fabsf(tt));
                if (dd <= RADIUS_F) {
                    int pid = __float_as_int(p.w);
                    int slot = atomicAdd(&scnt_s, 1);
                    if (slot < CAPK) {
                        key[slot] = (((ull)__float_as_uint(dd)) << 32) | (unsigned)pid;
                        pos_s[slot] = p;
                    }
                }
            }
        }
    }

    // top-64 by (d_bits, pid); selb stores SLOT index
    int n = min(scnt_s, CAPK);
    int nsel = min(n, 64);
    int n64 = (n + 63) & ~63;
    if (lane < n64 - n) key[n + lane] = ~0ull;
    if (n > 64) {
        for (int i = lane; i < n; i += 64) {
            ull ki = key[i];
            int r = 0;
            for (int j = 0; j < n64; j += 8) {
#pragma unroll
                for (int jj = 0; jj < 8; ++jj)
                    r += (key[j + jj] < ki) ? 1 : 0;
            }
            if (r < 64) selb[r] = i;
        }
    } else {
        for (int i = lane; i < n; i += 64) selb[i] = i;
    }

    // emit dense f16 feature rows [64][16], zero-padded (from LDS pos)
    {
        _Float16 z = (_Float16)0.f;
        f16x8 lo8 = {z, z, z, z, z, z, z, z};
        if (lane < nsel) {
            float4 p = pos_s[selb[lane]];
            lo8[0] = (_Float16)p.x; lo8[1] = (_Float16)p.y; lo8[2] = (_Float16)p.z;
            lo8[3] = (_Float16)(p.x - cc.x);
            lo8[4] = (_Float16)(p.y - cc.y);
            lo8[5] = (_Float16)(p.z - cc.z);
        }
        f16x8 hi8 = {z, z, z, z, z, z, z, z};
        _Float16* fr = featG + (size_t)c * 1024 + lane * 16;
        *(f16x8*)(fr + 0) = lo8;
        *(f16x8*)(fr + 8) = hi8;
    }
    if (lane == 0) nselG[c] = nsel;
}

// -------- K5: 4-wave cooperative MLP, h double-buffered (2 barriers) ------
__global__ __launch_bounds__(256) void sa_mlp4_kernel(
    const _Float16* __restrict__ featG, const int* __restrict__ nselG,
    const _Float16* __restrict__ wf16,
    const float* __restrict__ b1, const float* __restrict__ b2,
    const float* __restrict__ b3, float* __restrict__ out) {

    __shared__ __align__(16) _Float16 h1[4096];      // [64][64] swizzled
    __shared__ __align__(16) _Float16 h2[4096];

    int t = threadIdx.x, w = t >> 6, lane = t & 63;
    int r16 = lane & 15, g = lane >> 4;
    int c = blockIdx.x;
    int nsel = nselG[c];
    const _Float16* fG = featG + (size_t)c * 1024;

    // per-wave weight slices -> registers (coalesced, L2-hot, loaded once)
    f16x4 F1  = ((const f16x4*)wf16)[w * 64 + lane];
    f16x8 FA2 = ((const f16x8*)(wf16 + 1024))[w * 64 + lane];
    f16x8 FB2 = ((const f16x8*)(wf16 + 3072))[w * 64 + lane];
    f16x8 FA3a = ((const f16x8*)(wf16 + 5120))[(2 * w + 0) * 64 + lane];
    f16x8 FA3b = ((const f16x8*)(wf16 + 5120))[(2 * w + 1) * 64 + lane];
    f16x8 FB3a = ((const f16x8*)(wf16 + 9216))[(2 * w + 0) * 64 + lane];
    f16x8 FB3b = ((const f16x8*)(wf16 + 9216))[(2 * w + 1) * 64 + lane];
    float B1 = b1[w * 16 + r16];
    float B2 = b2[w * 16 + r16];
    float B3a = b3[(2 * w + 0) * 16 + r16];
    float B3b = b3[(2 * w + 1) * 16 + r16];

    // ---- L1: A-frags straight from featG; write h1 ----
    {
        f16x4 a1[4];
#pragma unroll
        for (int m = 0; m < 4; ++m)
            a1[m] = *(const f16x4*)&fG[(m * 16 + r16) * 16 + g * 4];
        int col = w * 16 + r16;
#pragma unroll
        for (int m = 0; m < 4; ++m) {
            f32x4 acc = {B1, B1, B1, B1};
            acc = __builtin_amdgcn_mfma_f32_16x16x16f16(a1[m], F1, acc, 0, 0, 0);
#pragma unroll
            for (int reg = 0; reg < 4; ++reg) {
                int row = m * 16 + g * 4 + reg;
                h1[row * 64 + (col ^ ((row & 7) << 3))] =
                    (_Float16)fmaxf(acc[reg], 0.f);
            }
        }
    }
    __syncthreads();

    // ---- L2: read h1, write h2 (no anti-dependency barrier) ----
    {
        int col = w * 16 + r16;
#pragma unroll
        for (int m = 0; m < 4; ++m) {
            int row = m * 16 + r16;
            f16x8 aA = *(const f16x8*)&h1[row * 64 + ((g * 8) ^ ((row & 7) << 3))];
            f16x8 aB = *(const f16x8*)&h1[row * 64 + ((32 + g * 8) ^ ((row & 7) << 3))];
            f32x4 acc = {B2, B2, B2, B2};
            acc = __builtin_amdgcn_mfma_f32_16x16x32_f16(aA, FA2, acc, 0, 0, 0);
            acc = __builtin_amdgcn_mfma_f32_16x16x32_f16(aB, FB2, acc, 0, 0, 0);
#pragma unroll
            for (int reg = 0; reg < 4; ++reg) {
                int row2 = m * 16 + g * 4 + reg;
                h2[row2 * 64 + (col ^ ((row2 & 7) << 3))] =
                    (_Float16)fmaxf(acc[reg], 0.f);
            }
        }
    }
    __syncthreads();

    // ---- L3: read h2; wave w -> cols (2w..2w+1)*16; masked max ----
    {
        f16x8 a3[4][2];
#pragma unroll
        for (int m = 0; m < 4; ++m)
#pragma unroll
            for (int kt = 0; kt < 2; ++kt) {
                int row = m * 16 + r16;
                int k0 = kt * 32 + g * 8;
                a3[m][kt] = *(const f16x8*)&h2[row * 64 + (k0 ^ ((row & 7) << 3))];
            }
        float ninf = __int_as_float(0xff800000);
#pragma unroll
        for (int q = 0; q < 2; ++q) {
            float bb = q ? B3b : B3a;
            f16x8 fa = q ? FA3b : FA3a;
            f16x8 fb = q ? FB3b : FB3a;
            float vm = ninf;
#pragma unroll
            for (int m = 0; m < 4; ++m) {
                f32x4 acc = {bb, bb, bb, bb};
                acc = __builtin_amdgcn_mfma_f32_16x16x32_f16(a3[m][0], fa, acc, 0, 0, 0);
                acc = __builtin_amdgcn_mfma_f32_16x16x32_f16(a3[m][1], fb, acc, 0, 0, 0);
#pragma unroll
                for (int reg = 0; reg < 4; ++reg) {
                    int row = m * 16 + g * 4 + reg;
                    if (row < nsel) vm = fmaxf(vm, acc[reg]);
                }
            }
            vm = fmaxf(vm, __shfl_xor(vm, 16));
            vm = fmaxf(vm, __shfl_xor(vm, 32));
            if (lane < 16)
                out[(size_t)c * 128 + (2 * w + q) * 16 + lane] = vm;
        }
    }
}

extern "C" void kernel_launch(void* const* d_in, const int* in_sizes, int n_in,
                              void* d_out, int out_size, void* d_ws, size_t ws_size,
                              hipStream_t stream) {
    const float* vtx = (const float*)d_in[0];
    const int* cidx  = (const int*)d_in[1];
    const float* W1  = (const float*)d_in[2];
    const float* b1  = (const float*)d_in[3];
    const float* W2  = (const float*)d_in[4];
    const float* b2  = (const float*)d_in[5];
    const float* W3  = (const float*)d_in[6];
    const float* b3  = (const float*)d_in[7];
    float* out = (float*)d_out;

    int N = in_sizes[0] / 3;   // 65536
    int M = in_sizes[1];       // 4096

    char* ws = (char*)d_ws;
    size_t off = 0;
    float4* sorted4 = (float4*)(ws + off); off += (size_t)N * 16;
    float4* cpos4   = (float4*)(ws + off); off += (size_t)M * 16;
    int* cellCnt    = (int*)(ws + off);    off += (size_t)NC * 4;
    int* cursor     = (int*)(ws + off);    off += 16;
    int* cellStart  = (int*)(ws + off);    off += (size_t)NC * 4;
    int* cellEnd    = (int*)(ws + off);    off += (size_t)NC * 4;
    int* cellCur    = (int*)(ws + off);    off += (size_t)NC * 4;
    _Float16* featG = (_Float16*)(ws + off); off += (size_t)M * 1024 * 2;
    int* nselG      = (int*)(ws + off);    off += (size_t)M * 4;
    _Float16* wf16  = (_Float16*)(ws + off);

    sa_zero_kernel<<<256, 256, 0, stream>>>((int4*)cellCnt, (NC * 4 + 16) / 16);
    sa_count_kernel<<<512, 256, 0, stream>>>(vtx, cellCnt, N, W1, W2, W3, wf16);
    sa_offsets_kernel<<<NC / CHUNK, 256, 0, stream>>>(cellCnt, cellStart,
                                                      cellEnd, cellCur, cursor);
    sa_scatter_kernel<<<(N + 255) / 256, 256, 0, stream>>>(vtx, cellCur,
                                                           sorted4, cidx,
                                                           cpos4, N, M);
    sa_collect_kernel<<<M, 64, 0, stream>>>(cpos4, sorted4,
                                            cellStart, cellEnd, featG, nselG);
    sa_mlp4_kernel<<<M, 256, 0, stream>>>(featG, nselG, wf16,
                                          b1, b2, b3, out);
}

// Round 20
// 61.417 us; speedup vs baseline: 1.2905x; 1.0510x over previous
//
#include <hip/hip_runtime.h>
#include <hip/hip_bf16.h>

#define GD     50          // grid cells per dim
#define NC     (GD*GD*GD)  // 125000
#define CHUNK  250         // cells per offsets block; 250%50==0 keeps x-rows intact
#define CAPK   256         // in-radius candidate capacity per centroid
#define RADIUS_F 0.2f
#define R2SAFE 0.0401f

typedef unsigned long long ull;
typedef __attribute__((ext_vector_type(4))) _Float16 f16x4;
typedef __attribute__((ext_vector_type(8))) _Float16 f16x8;
typedef __attribute__((ext_vector_type(4))) float    f32x4;

__device__ __forceinline__ int cellcoord(float v) {
    int c = (int)floorf((v + 5.0f) * 5.0f);
    return min(max(c, 0), GD - 1);
}

// Fragment-order weight layout in wf16 (13312 f16):
//   [0,1024)      F1 [nn=4][lane=64][4]
//   [1024,3072)   FA2[nn=4][lane=64][8]
//   [3072,5120)   FB2[nn=4][lane=64][8]
//   [5120,9216)   FA3[nn=8][lane=64][8]
//   [9216,13312)  FB3[nn=8][lane=64][8]

// -------- K0: zero cellCnt + cursor ---------------------------------------
__global__ void sa_zero_kernel(int4* __restrict__ dst, int n4) {
    int i = blockIdx.x * blockDim.x + threadIdx.x;
    int stride = gridDim.x * blockDim.x;
    for (; i < n4; i += stride) dst[i] = make_int4(0, 0, 0, 0);
}

// -------- K1: count cells + frag-order f16 weights ------------------------
__global__ void sa_count_kernel(const float* __restrict__ vtx,
                                int* __restrict__ cellCnt, int N,
                                const float* __restrict__ W1,
                                const float* __restrict__ W2,
                                const float* __restrict__ W3,
                                _Float16* __restrict__ wf16) {
    int i = blockIdx.x * blockDim.x + threadIdx.x;
    int stride = gridDim.x * blockDim.x;
    for (int p = i; p < N; p += stride) {
        float x = vtx[3 * p], y = vtx[3 * p + 1], z = vtx[3 * p + 2];
        int cc = (cellcoord(z) * GD + cellcoord(y)) * GD + cellcoord(x);
        atomicAdd(&cellCnt[cc], 1);
    }
    for (int e = i; e < 1024; e += stride) {
        int nn = e >> 8, lane = (e >> 2) & 63, j = e & 3;
        int col = nn * 16 + (lane & 15), k = (lane >> 4) * 4 + j;
        wf16[e] = (k < 6) ? (_Float16)W1[k * 64 + col] : (_Float16)0.f;
    }
    for (int e = i; e < 2048; e += stride) {
        int nn = e >> 9, lane = (e >> 3) & 63, j = e & 7;
        int col = nn * 16 + (lane & 15), k = (lane >> 4) * 8 + j;
        wf16[1024 + e] = (_Float16)W2[k * 64 + col];
        wf16[3072 + e] = (_Float16)W2[(k + 32) * 64 + col];
    }
    for (int e = i; e < 4096; e += stride) {
        int nn = e >> 9, lane = (e >> 3) & 63, j = e & 7;
        int col = nn * 16 + (lane & 15), k = (lane >> 4) * 8 + j;
        wf16[5120 + e] = (_Float16)W3[k * 128 + col];
        wf16[9216 + e] = (_Float16)W3[(k + 32) * 128 + col];
    }
}

// -------- K2: CSR offsets, 250-cell x-row-aligned chunks; also cellEnd ----
__global__ __launch_bounds__(256) void sa_offsets_kernel(
    const int* __restrict__ cellCnt, int* __restrict__ cellStart,
    int* __restrict__ cellEnd, int* __restrict__ cellCur,
    int* __restrict__ cursor) {
    __shared__ int sc[256];
    __shared__ int base_s;
    int t = threadIdx.x;
    int i = blockIdx.x * CHUNK + t;
    int c = (t < CHUNK) ? cellCnt[i] : 0;
    sc[t] = c;
    __syncthreads();
    for (int d = 1; d < 256; d <<= 1) {
        int o = (t >= d) ? sc[t - d] : 0;
        __syncthreads();
        sc[t] += o;
        __syncthreads();
    }
    if (t == 255) base_s = atomicAdd(cursor, sc[255]);
    __syncthreads();
    int start = base_s + sc[t] - c;
    if (t < CHUNK) {
        cellStart[i] = start;
        cellEnd[i] = start + c;
        cellCur[i] = start;
    }
}

// -------- K3: scatter points (pid packed in w); build cpos4 ---------------
__global__ void sa_scatter_kernel(const float* __restrict__ vtx,
                                  int* __restrict__ cellCur,
                                  float4* __restrict__ sorted4,
                                  const int* __restrict__ cidx,
                                  float4* __restrict__ cpos4,
                                  int N, int M) {
    int p = blockIdx.x * blockDim.x + threadIdx.x;
    if (p < N) {
        float x = vtx[3 * p], y = vtx[3 * p + 1], z = vtx[3 * p + 2];
        int cc = (cellcoord(z) * GD + cellcoord(y)) * GD + cellcoord(x);
        int pos = atomicAdd(&cellCur[cc], 1);
        sorted4[pos] = make_float4(x, y, z, __int_as_float(p));
    }
    if (p < M) {
        int i = cidx[p];
        float x = vtx[3 * i], y = vtx[3 * i + 1], z = vtx[3 * i + 2];
        float sn = fmaf(z, z, fmaf(y, y, x * x));
        cpos4[p] = make_float4(x, y, z, sn);
    }
}

// -------- K4: fused 4-wave cooperative collect + top-64 + MLP -------------
// One centroid per 256-thread block. All 4 waves stream chunks; 256-thread
// rank-select; MLP with per-wave register weight slices (r19 structure).
__global__ __launch_bounds__(256) void sa_fused4_kernel(
    const float4* __restrict__ cpos4, const float4* __restrict__ sorted4,
    const int* __restrict__ cellStart, const int* __restrict__ cellEnd,
    const _Float16* __restrict__ wf16,
    const float* __restrict__ b1, const float* __restrict__ b2,
    const float* __restrict__ b3, float* __restrict__ out) {

    __shared__ __align__(16) ull key[CAPK];          // 2 KB
    __shared__ __align__(16) float4 pos_s[CAPK];     // 4 KB
    __shared__ __align__(16) _Float16 featb[1024];   // 2 KB
    __shared__ __align__(16) _Float16 h1[4096];      // 8 KB
    __shared__ __align__(16) _Float16 h2[4096];      // 8 KB
    __shared__ int selb[64];
    __shared__ int chdesc[64];
    __shared__ int scnt_s;

    int t = threadIdx.x, w = t >> 6, lane = t & 63;
    int r16 = lane & 15, g = lane >> 4;
    int c = blockIdx.x;
    float4 cc = cpos4[c];

    // prefill sentinels (entries never overwritten rank last)
    key[t] = ~0ull;
    if (t == 0) scnt_s = 0;

    // ---- row bounds (identical in all 4 waves) ----
    int cx = cellcoord(cc.x), cy = cellcoord(cc.y), cz = cellcoord(cc.z);
    int x0 = max(cx - 1, 0), x1 = min(cx + 1, GD - 1), lx = x1 - x0 + 1;
    int y0 = max(cy - 1, 0), y1 = min(cy + 1, GD - 1), ly = y1 - y0 + 1;
    int z0 = max(cz - 1, 0), z1 = min(cz + 1, GD - 1), lz = z1 - z0 + 1;
    int nrow = ly * lz;

    int rstart = 0, rlen = 0;
    if (lane < nrow) {
        int iy = lane % ly, iz = lane / ly;
        int gy = y0 + iy, gz = z0 + iz;
        float ylo = (gy == 0) ? -1e30f : gy * 0.2f - 5.0f;
        float yhi = (gy == GD - 1) ? 1e30f : (gy + 1) * 0.2f - 5.0f;
        float zlo = (gz == 0) ? -1e30f : gz * 0.2f - 5.0f;
        float zhi = (gz == GD - 1) ? 1e30f : (gz + 1) * 0.2f - 5.0f;
        float dy = fmaxf(0.f, fmaxf(ylo - cc.y, cc.y - yhi));
        float dz = fmaxf(0.f, fmaxf(zlo - cc.z, cc.z - zhi));
        if (fmaf(dz, dz, dy * dy) <= R2SAFE) {
            int cell0 = (gz * GD + gy) * GD + x0;
            int cellL = cell0 + (lx - 1);
            rstart = cellStart[cell0];
            rlen = cellEnd[cellL] - rstart;
        }
    }
    int nch = (rlen + 63) >> 6;
    int ip = nch;
#pragma unroll
    for (int d = 1; d < 16; d <<= 1) {
        int o = __shfl_up(ip, d);
        if (lane >= d) ip += o;
    }
    int C = __shfl(ip, nrow - 1);
    int ebase = ip - nch;
    if (w == 0 && lane < nrow) {
        for (int k = 0; k < nch; ++k) {
            int st = rstart + (k << 6);
            int ln = min(64, rlen - (k << 6));
            chdesc[ebase + k] = st | (ln << 20);
        }
    }
    __syncthreads();

    // ---- stream chunks, 4 waves round-robin ----
    for (int ch = w; ch < C; ch += 4) {
        int d0 = chdesc[ch];
        int st = d0 & 0xFFFFF, ln = d0 >> 20;
        if (lane < ln) {
            int sp = st + lane;
            float4 p = sorted4[sp];
            float psn = fmaf(p.z, p.z, fmaf(p.y, p.y, p.x * p.x));
            float dot = fmaf(p.z, cc.z, fmaf(p.y, cc.y, p.x * cc.x));
            float tt = fmaf(-2.f, dot, cc.w) + psn;
            if (tt <= R2SAFE) {
                float dd = sqrtf(fabsf(tt));
                if (dd <= RADIUS_F) {
                    int pid = __float_as_int(p.w);
                    int slot = atomicAdd(&scnt_s, 1);
                    if (slot < CAPK) {
                        key[slot] = (((ull)__float_as_uint(dd)) << 32) | (unsigned)pid;
                        pos_s[slot] = p;
                    }
                }
            }
        }
    }
    __syncthreads();

    // ---- per-wave weight slices (issued here, latency hides under rank) --
    f16x4 F1  = ((const f16x4*)wf16)[w * 64 + lane];
    f16x8 FA2 = ((const f16x8*)(wf16 + 1024))[w * 64 + lane];
    f16x8 FB2 = ((const f16x8*)(wf16 + 3072))[w * 64 + lane];
    f16x8 FA3a = ((const f16x8*)(wf16 + 5120))[(2 * w + 0) * 64 + lane];
    f16x8 FA3b = ((const f16x8*)(wf16 + 5120))[(2 * w + 1) * 64 + lane];
    f16x8 FB3a = ((const f16x8*)(wf16 + 9216))[(2 * w + 0) * 64 + lane];
    f16x8 FB3b = ((const f16x8*)(wf16 + 9216))[(2 * w + 1) * 64 + lane];
    float B1 = b1[w * 16 + r16];
    float B2 = b2[w * 16 + r16];
    float B3a = b3[(2 * w + 0) * 16 + r16];
    float B3b = b3[(2 * w + 1) * 16 + r16];

    // ---- top-64: 256-thread padded unroll-8 rank (selb = slot index) ----
    int n = min(scnt_s, CAPK);
    int nsel = min(n, 64);
    int n64 = (n + 63) & ~63;
    if (n > 64) {
        for (int i = t; i < n; i += 256) {
            ull ki = key[i];
            int r = 0;
            for (int j = 0; j < n64; j += 8) {
#pragma unroll
                for (int jj = 0; jj < 8; ++jj)
                    r += (key[j + jj] < ki) ? 1 : 0;
            }
            if (r < 64) selb[r] = i;
        }
    } else {
        for (int i = t; i < n; i += 256) selb[i] = i;
    }
    __syncthreads();

    // ---- feature rows -> featb [64][16] f16, zero-padded ----
    if (t < 64) {
        _Float16 z = (_Float16)0.f;
        f16x8 lo8 = {z, z, z, z, z, z, z, z};
        if (t < nsel) {
            float4 p = pos_s[selb[t]];
            lo8[0] = (_Float16)p.x; lo8[1] = (_Float16)p.y; lo8[2] = (_Float16)p.z;
            lo8[3] = (_Float16)(p.x - cc.x);
            lo8[4] = (_Float16)(p.y - cc.y);
            lo8[5] = (_Float16)(p.z - cc.z);
        }
        f16x8 hi8 = {z, z, z, z, z, z, z, z};
        *(f16x8*)&featb[t * 16 + 0] = lo8;
        *(f16x8*)&featb[t * 16 + 8] = hi8;
    }
    __syncthreads();

    // ---- L1: featb @ W1 -> relu -> h1 (wave w owns cols w*16..) ----
    {
        f16x4 a1[4];
#pragma unroll
        for (int m = 0; m < 4; ++m)
            a1[m] = *(const f16x4*)&featb[(m * 16 + r16) * 16 + g * 4];
        int col = w * 16 + r16;
#pragma unroll
        for (int m = 0; m < 4; ++m) {
            f32x4 acc = {B1, B1, B1, B1};
            acc = __builtin_amdgcn_mfma_f32_16x16x16f16(a1[m], F1, acc, 0, 0, 0);
#pragma unroll
            for (int reg = 0; reg < 4; ++reg) {
                int row = m * 16 + g * 4 + reg;
                h1[row * 64 + (col ^ ((row & 7) << 3))] =
                    (_Float16)fmaxf(acc[reg], 0.f);
            }
        }
    }
    __syncthreads();

    // ---- L2: read h1, write h2 ----
    {
        int col = w * 16 + r16;
#pragma unroll
        for (int m = 0; m < 4; ++m) {
            int row = m * 16 + r16;
            f16x8 aA = *(const f16x8*)&h1[row * 64 + ((g * 8) ^ ((row & 7) << 3))];
            f16x8 aB = *(const f16x8*)&h1[row * 64 + ((32 + g * 8) ^ ((row & 7) << 3))];
            f32x4 acc = {B2, B2, B2, B2};
            acc = __builtin_amdgcn_mfma_f32_16x16x32_f16(aA, FA2, acc, 0, 0, 0);
            acc = __builtin_amdgcn_mfma_f32_16x16x32_f16(aB, FB2, acc, 0, 0, 0);
#pragma unroll
            for (int reg = 0; reg < 4; ++reg) {
                int row2 = m * 16 + g * 4 + reg;
                h2[row2 * 64 + (col ^ ((row2 & 7) << 3))] =
                    (_Float16)fmaxf(acc[reg], 0.f);
            }
        }
    }
    __syncthreads();

    // ---- L3: read h2; wave w -> cols (2w..2w+1)*16; masked max ----
    {
        f16x8 a3[4][2];
#pragma unroll
        for (int m = 0; m < 4; ++m)
#pragma unroll
            for (int kt = 0; kt < 2; ++kt) {
                int row = m * 16 + r16;
                int k0 = kt * 32 + g * 8;
                a3[m][kt] = *(const f16x8*)&h2[row * 64 + (k0 ^ ((row & 7) << 3))];
            }
        float ninf = __int_as_float(0xff800000);
#pragma unroll
        for (int q = 0; q < 2; ++q) {
            float bb = q ? B3b : B3a;
            f16x8 fa = q ? FA3b : FA3a;
            f16x8 fb = q ? FB3b : FB3a;
            float vm = ninf;
#pragma unroll
            for (int m = 0; m < 4; ++m) {
                f32x4 acc = {bb, bb, bb, bb};
                acc = __builtin_amdgcn_mfma_f32_16x16x32_f16(a3[m][0], fa, acc, 0, 0, 0);
                acc = __builtin_amdgcn_mfma_f32_16x16x32_f16(a3[m][1], fb, acc, 0, 0, 0);
#pragma unroll
                for (int reg = 0; reg < 4; ++reg) {
                    int row = m * 16 + g * 4 + reg;
                    if (row < nsel) vm = fmaxf(vm, acc[reg]);
                }
            }
            vm = fmaxf(vm, __shfl_xor(vm, 16));
            vm = fmaxf(vm, __shfl_xor(vm, 32));
            if (lane < 16)
                out[(size_t)c * 128 + (2 * w + q) * 16 + lane] = vm;
        }
    }
}

extern "C" void kernel_launch(void* const* d_in, const int* in_sizes, int n_in,
                              void* d_out, int out_size, void* d_ws, size_t ws_size,
                              hipStream_t stream) {
    const float* vtx = (const float*)d_in[0];
    const int* cidx  = (const int*)d_in[1];
    const float* W1  = (const float*)d_in[2];
    const float* b1  = (const float*)d_in[3];
    const float* W2  = (const float*)d_in[4];
    const float* b2  = (const float*)d_in[5];
    const float* W3  = (const float*)d_in[6];
    const float* b3  = (const float*)d_in[7];
    float* out = (float*)d_out;

    int N = in_sizes[0] / 3;   // 65536
    int M = in_sizes[1];       // 4096

    char* ws = (char*)d_ws;
    size_t off = 0;
    float4* sorted4 = (float4*)(ws + off); off += (size_t)N * 16;
    float4* cpos4   = (float4*)(ws + off); off += (size_t)M * 16;
    int* cellCnt    = (int*)(ws + off);    off += (size_t)NC * 4;
    int* cursor     = (int*)(ws + off);    off += 16;
    int* cellStart  = (int*)(ws + off);    off += (size_t)NC * 4;
    int* cellEnd    = (int*)(ws + off);    off += (size_t)NC * 4;
    int* cellCur    = (int*)(ws + off);    off += (size_t)NC * 4;
    _Float16* wf16  = (_Float16*)(ws + off);

    sa_zero_kernel<<<256, 256, 0, stream>>>((int4*)cellCnt, (NC * 4 + 16) / 16);
    sa_count_kernel<<<512, 256, 0, stream>>>(vtx, cellCnt, N, W1, W2, W3, wf16);
    sa_offsets_kernel<<<NC / CHUNK, 256, 0, stream>>>(cellCnt, cellStart,
                                                      cellEnd, cellCur, cursor);
    sa_scatter_kernel<<<(N + 255) / 256, 256, 0, stream>>>(vtx, cellCur,
                                                           sorted4, cidx,
                                                           cpos4, N, M);
    sa_fused4_kernel<<<M, 256, 0, stream>>>(cpos4, sorted4,
                                            cellStart, cellEnd, wf16,
                                            b1, b2, b3, out);
}